// Round 3
// baseline (108.244 us; speedup 1.0000x reference)
//
#include <hip/hip_runtime.h>

// ConvTranspose2d (C_in=256 -> C_out=128, k=4, stride=2, pad=1), x 128x128 -> out 256x256.
// out[o, 2*yo+ry, 2*xo+rx] = sum_ci sum_{a,b} X[ci, yo+ry-1+a, xo+rx-1+b] * W[o,ci,2a+ry,2b+rx] + bias[o]
// bf16 MFMA 32x32x16. 16 waves/block = 4 classes x 2 o-halves x 2 spatial-halves, full K per wave.

typedef __attribute__((ext_vector_type(8))) short bf16x8;
typedef __attribute__((ext_vector_type(16))) float f32x16;

#define CI 256
#define CO 128
#define HW 128
#define YO_TILE 4
#define XO_TILE 16
#define CELLS_R 6               // yo rows needed: Y0-1 .. Y0+4
#define CELLS_C 18              // xo cols needed: X0-1 .. X0+16
#define NCELLS (CELLS_R * CELLS_C)   // 108 cells, each 256 ci * 2B = 512B
#define LDS_BYTES (NCELLS * 512)     // 55296 B

static __device__ __forceinline__ unsigned short f2bf(float f) {
  union { float f; unsigned u; } v; v.f = f;
  return (unsigned short)((v.u + 0x7FFFu + ((v.u >> 16) & 1u)) >> 16);  // RTNE
}

// ---- Pass 1a: x[ci][h][w] f32 -> xbT[h*128+w][ci] bf16. 64x64 tile via LDS. ----
__global__ __launch_bounds__(256) void transpose_x_kernel(const float* __restrict__ x,
                                                          unsigned short* __restrict__ xbT) {
  __shared__ unsigned short tileT[64][68];   // [hw][ci], padded
  const int hw0 = blockIdx.x * 64;
  const int ci0 = blockIdx.y * 64;
  const int tid = threadIdx.x;
#pragma unroll
  for (int it = 0; it < 4; ++it) {
    const int p = it * 256 + tid;          // 0..1023
    const int ci_r = p >> 4;               // 0..63
    const int c4 = p & 15;                 // float4 index along hw
    const float4 v = *(const float4*)(x + (size_t)(ci0 + ci_r) * (HW * HW) + hw0 + c4 * 4);
    tileT[c4 * 4 + 0][ci_r] = f2bf(v.x);
    tileT[c4 * 4 + 1][ci_r] = f2bf(v.y);
    tileT[c4 * 4 + 2][ci_r] = f2bf(v.z);
    tileT[c4 * 4 + 3][ci_r] = f2bf(v.w);
  }
  __syncthreads();
#pragma unroll
  for (int it = 0; it < 2; ++it) {
    const int p = it * 256 + tid;          // 0..511
    const int cg = p & 7;                  // 8-ci group
    const int hw = p >> 3;                 // 0..63
    const bf16x8 v = *(const bf16x8*)&tileT[hw][cg * 8];
    *(bf16x8*)(xbT + (size_t)(hw0 + hw) * CI + ci0 + cg * 8) = v;
  }
}

// ---- Pass 1b: W[o][ci][tap] f32 -> Wb[tap][cbG][o][ci_lo] bf16 ----
// Thread reads one float4 (4 consecutive taps of one (o,ci)) coalesced; 4 bf16 scatter stores.
__global__ __launch_bounds__(256) void reorg_w_kernel(const float* __restrict__ W,
                                                      unsigned short* __restrict__ Wb) {
  const int tid = blockIdx.x * 256 + threadIdx.x;   // 0..131071
  const int f = tid * 4;
  const int tap0 = f & 15;
  const int ci = (f >> 4) & 255;
  const int o = f >> 12;
  const float4 v = *(const float4*)(W + f);
  const int base = ((ci >> 4) * CO + o) * 16 + (ci & 15);   // cbG*2048 + o*16 + ci_lo
  Wb[(tap0 + 0) * 32768 + base] = f2bf(v.x);
  Wb[(tap0 + 1) * 32768 + base] = f2bf(v.y);
  Wb[(tap0 + 2) * 32768 + base] = f2bf(v.z);
  Wb[(tap0 + 3) * 32768 + base] = f2bf(v.w);
}

// ---- Main kernel: grid (8,32), 1024 threads = 16 waves = 4 cls x 2 mh x 2 sph ----
// Wave tile: M=64 (2 mt of 32 o), N=32 (2 yo x 16 xo), K=1024 (4 taps x 16 ci-chunks).
__global__ __launch_bounds__(1024, 4) void tconv_mfma_kernel(
    const unsigned short* __restrict__ xbT,
    const unsigned short* __restrict__ Wb,
    const float* __restrict__ bias,
    float* __restrict__ out) {
  __shared__ __align__(16) unsigned char LDS[LDS_BYTES];
  const int tid = threadIdx.x;
  const int X0 = blockIdx.x * XO_TILE;
  const int Y0 = blockIdx.y * YO_TILE;

  // stage X tile once: cell (r,c) = 256 ci bf16; 16B slot s stored at (s^c) (latin square)
  for (int e = tid; e < NCELLS * 32; e += 1024) {
    const int s = e & 31;
    const int cell = e >> 5;
    const int c = cell % CELLS_C;
    const int r = cell / CELLS_C;
    const int gr = Y0 - 1 + r;
    const int gc = X0 - 1 + c;
    uint4 val = make_uint4(0u, 0u, 0u, 0u);
    if (gr >= 0 && gr < HW && gc >= 0 && gc < HW)
      val = *(const uint4*)(xbT + ((gr * HW + gc) * CI + s * 8));
    *(uint4*)(LDS + cell * 512 + ((s ^ c) * 16)) = val;
  }
  __syncthreads();

  const int lane = tid & 63;
  const int wave = tid >> 6;
  const int cls = wave & 3;
  const int ry = cls >> 1, rx = cls & 1;
  const int mh = (wave >> 2) & 1;     // o-half: o in [mh*64, mh*64+64)
  const int sph = wave >> 3;          // spatial half: yo pair
  const int l31 = lane & 31;
  const int lhi = lane >> 5;          // k sub-group: k = lhi*8 + j
  const int nrow = l31 >> 4;          // yo offset within pair
  const int ncol = l31 & 15;          // xo offset

  f32x16 acc[2];
#pragma unroll
  for (int mt = 0; mt < 2; ++mt)
#pragma unroll
    for (int t = 0; t < 16; ++t) acc[mt][t] = 0.0f;

  // K loop: 4 taps x 16 ci-chunks(16); no barriers
#pragma unroll
  for (int a = 0; a < 2; ++a) {
#pragma unroll
    for (int b = 0; b < 2; ++b) {
      const int tap = (2 * a + ry) * 4 + (2 * b + rx);
      const int c_l = ncol + rx + b;                 // 0..17
      const int r_base = sph * 2 + nrow + ry + a;    // 0..5
      const int cellbase = (r_base * CELLS_C + c_l) * 512;
      const unsigned short* wt = Wb + tap * 32768 + (mh * 64 + l31) * 16 + lhi * 8;
#pragma unroll
      for (int cb = 0; cb < 16; ++cb) {
        const int s_idx = cb * 2 + lhi;
        const bf16x8 bfrag = *(const bf16x8*)(LDS + cellbase + ((s_idx ^ c_l) * 16));
        const unsigned short* wk = wt + cb * 2048;
#pragma unroll
        for (int mt = 0; mt < 2; ++mt)
          acc[mt] = __builtin_amdgcn_mfma_f32_32x32x16_bf16(
              *(const bf16x8*)(wk + mt * 512), bfrag, acc[mt], 0, 0, 0);
      }
    }
  }

  // direct store, no reduction
  const int yo = Y0 + sph * 2 + nrow;
  const int xo = X0 + ncol;
  const int y = 2 * yo + ry;
  const int xg = 2 * xo + rx;
#pragma unroll
  for (int mt = 0; mt < 2; ++mt)
#pragma unroll
    for (int t = 0; t < 16; ++t) {
      const int rowD = (t & 3) + 4 * lhi + 8 * (t >> 2);
      const int o = mh * 64 + mt * 32 + rowD;
      out[((size_t)o << 16) + (y << 8) + xg] = acc[mt][t] + bias[o];
    }
}

extern "C" void kernel_launch(void* const* d_in, const int* in_sizes, int n_in,
                              void* d_out, int out_size, void* d_ws, size_t ws_size,
                              hipStream_t stream) {
  const float* x = (const float*)d_in[0];     // (256,128,128)
  const float* W = (const float*)d_in[1];     // (128,256,4,4)
  const float* b = (const float*)d_in[2];     // (128,)
  float* out = (float*)d_out;                 // (128,256,256)

  unsigned short* xbT = (unsigned short*)d_ws;            // 8 MB
  unsigned short* Wb = xbT + (size_t)CI * HW * HW;        // 1 MB

  transpose_x_kernel<<<dim3((HW * HW) / 64, CI / 64), dim3(256), 0, stream>>>(x, xbT);
  reorg_w_kernel<<<dim3(512), dim3(256), 0, stream>>>(W, Wb);
  tconv_mfma_kernel<<<dim3(HW / XO_TILE, HW / YO_TILE), dim3(1024), 0, stream>>>(xbT, Wb, b, out);
}